// Round 11
// baseline (899.852 us; speedup 1.0000x reference)
//
#include <hip/hip_runtime.h>
#include <hip/hip_bf16.h>

typedef __hip_bfloat16 bf16;
typedef __attribute__((ext_vector_type(8))) short s16x8;
typedef __attribute__((ext_vector_type(4))) float f32x4;

constexpr int cN = 128, cC = 64, cT = 64, cV = 25, cK = 3, cMID = 64, cKM = 192, cTV = 1600;
constexpr float cEPS = 1e-5f;

// BSS intermediates (no d_ws use). All rewritten before read each call.
__device__ float g_tmp[cN * cC * cV];
__device__ float g_x1 [cN * cKM * cV];
__device__ float g_x2 [cN * cKM * cV];
__device__ float g_ada[cN * cK * cV * cV];
// Per-channel Adyn in B-fragment order: [n][r][nf(2)][lane(64)][j(8)] bf16
__device__ ushort g_adF[(size_t)cN * cKM * 1024];          // 50.3 MB
// Folded weights in A-fragment order: [k-step][m-frag(12)][lane(64)][8]
__device__ ushort g_WpreF[2 * 12 * 512];
__device__ ushort g_WcatF[8 * 12 * 512];
__device__ float g_bpre [cKM];
__device__ float g_cterm[cKM];

__device__ __forceinline__ bf16  f2b(float v){ return __float2bfloat16(v); }
__device__ __forceinline__ ushort f2bu(float v){ return __builtin_bit_cast(ushort, __float2bfloat16(v)); }

// ---------------------------------------------------------------------------
// 0) fold bn into weights/biases; weights stored in A-frag order (bf16).
// ---------------------------------------------------------------------------
__global__ void k_fold(const float* __restrict__ Wpre, const float* __restrict__ bpre,
                       const float* __restrict__ bnpre,
                       const float* __restrict__ Wpost, const float* __restrict__ bpost,
                       const float* __restrict__ bnpost,
                       const float* __restrict__ Wdown, const float* __restrict__ bdown,
                       const float* __restrict__ bndown){
  __shared__ float sPre[cKM], sPost[cKM], sDown[cKM];
  int tid = threadIdx.x;
  if (tid < cKM){
    float sp = bnpre[tid] * rsqrtf(bnpre[3*cKM+tid] + cEPS);
    sPre[tid] = sp;
    g_bpre[tid] = bpre[tid]*sp + bnpre[cKM+tid] - bnpre[2*cKM+tid]*sp;
    float sP = bnpost[tid] * rsqrtf(bnpost[3*cKM+tid] + cEPS);
    float sD = bndown[tid] * rsqrtf(bndown[3*cKM+tid] + cEPS);
    sPost[tid] = sP; sDown[tid] = sD;
    g_cterm[tid] = bpost[tid]*sP + bnpost[cKM+tid] - bnpost[2*cKM+tid]*sP
                 + bdown[tid]*sD + bndown[cKM+tid] - bndown[2*cKM+tid]*sD;
  }
  __syncthreads();
  for (int idx = tid; idx < cKM*cC; idx += 256){
    int o = idx >> 6, k = idx & 63;
    int step = k >> 5, g = (k >> 3) & 3, j = k & 7;
    int dst = ((step*12 + (o>>4)) << 9) + (((g<<4) | (o&15)) << 3) + j;
    g_WpreF[dst] = f2bu(Wpre[idx] * sPre[o]);
  }
  for (int idx = tid; idx < cKM*256; idx += 256){
    int o = idx >> 8, k = idx & 255;
    float w = (k < cKM) ? Wpost[o*cKM + k] * sPost[o]
                        : Wdown[o*cC + (k - cKM)] * sDown[o];
    int step = k >> 5, g = (k >> 3) & 3, j = k & 7;
    int dst = ((step*12 + (o>>4)) << 9) + (((g<<4) | (o&15)) << 3) + j;
    g_WcatF[dst] = f2bu(w);
  }
}

// ---------------------------------------------------------------------------
// 1) g_tmp[n,c,v] = mean_t x[n,c,t,v]   coalesced via LDS.  grid = N*16.
// ---------------------------------------------------------------------------
__global__ __launch_bounds__(256) void gm_tmp(const float* __restrict__ x){
  __shared__ float xs[4 * cTV];
  int n = blockIdx.x >> 4, cg = blockIdx.x & 15;
  int tid = threadIdx.x;
  const float* xp = x + ((size_t)n*cC + cg*4)*cTV;
  for (int i = tid; i < 4*cTV; i += 256) xs[i] = xp[i];
  __syncthreads();
  if (tid < 100){
    int c = tid / 25, v = tid - c*25;
    float s = 0.f;
    #pragma unroll
    for (int t = 0; t < cT; ++t) s += xs[c*cTV + t*cV + v];
    g_tmp[(n*cC + cg*4 + c)*cV + v] = s * (1.f/cT);
  }
}

// ---------------------------------------------------------------------------
// 2) x1/x2 1x1 conv on mean
// ---------------------------------------------------------------------------
__global__ void gm_x1x2(const float* __restrict__ W1, const float* __restrict__ b1,
                        const float* __restrict__ W2, const float* __restrict__ b2){
  __shared__ float tl[cC * cV];
  __shared__ float w1[48 * cC];
  __shared__ float w2[48 * cC];
  int n = blockIdx.x >> 2, og = blockIdx.x & 3;
  int tid = threadIdx.x;
  int obase = og * 48;
  for (int i = tid; i < cC * cV; i += 256) tl[i] = g_tmp[n * cC * cV + i];
  for (int i = tid; i < 48 * cC; i += 256){
    w1[i] = W1[obase * cC + i];
    w2[i] = W2[obase * cC + i];
  }
  __syncthreads();
  for (int idx = tid; idx < 48 * cV; idx += 256){
    int j = idx / cV, v = idx % cV;
    int o = obase + j;
    float s1 = b1[o], s2 = b2[o];
    #pragma unroll
    for (int c = 0; c < cC; ++c){
      float t = tl[c * cV + v];
      s1 += w1[j * cC + c] * t;
      s2 += w2[j * cC + c] * t;
    }
    g_x1[((size_t)n * cKM + o) * cV + v] = s1;
    g_x2[((size_t)n * cKM + o) * cV + v] = s2;
  }
}

// ---------------------------------------------------------------------------
// 3) ada softmax (channel-shared part of Adyn)
// ---------------------------------------------------------------------------
__global__ void gm_ada(const float* __restrict__ beta){
  __shared__ float a1[cMID * cV];
  __shared__ float a2[cMID * cV];
  __shared__ float al[cV * cV];
  int b = blockIdx.x; int n = b / cK, k = b % cK;
  int tid = threadIdx.x;
  const float* p1 = g_x1 + ((size_t)n * cKM + k * cMID) * cV;
  const float* p2 = g_x2 + ((size_t)n * cKM + k * cMID) * cV;
  for (int i = tid; i < cMID * cV; i += 128){ a1[i] = p1[i]; a2[i] = p2[i]; }
  __syncthreads();
  for (int idx = tid; idx < cV * cV; idx += 128){
    int v = idx / cV, w = idx % cV;
    float s = 0.f;
    #pragma unroll
    for (int c = 0; c < cMID; ++c) s += a1[c * cV + v] * a2[c * cV + w];
    al[idx] = s;
  }
  __syncthreads();
  float b0 = beta[0];
  if (tid < cV){
    int w = tid;
    float m = -1e30f;
    for (int v = 0; v < cV; ++v) m = fmaxf(m, al[v * cV + w]);
    float s = 0.f;
    for (int v = 0; v < cV; ++v) s += expf(al[v * cV + w] - m);
    float inv = b0 / s;
    for (int v = 0; v < cV; ++v)
      g_ada[(size_t)b * cV * cV + v * cV + w] = expf(al[v * cV + w] - m) * inv;
  }
}

// ---------------------------------------------------------------------------
// 3b) Per-channel Adyn -> B-fragment order g_adF[n][r][nf][lane][8].
// ---------------------------------------------------------------------------
__global__ __launch_bounds__(256) void gm_adFk(const float* __restrict__ A,
                                               const float* __restrict__ alpha){
  int n = blockIdx.x / 24, rg = blockIdx.x % 24;
  int tid = threadIdx.x;
  float a0 = alpha[0];
  #pragma unroll 1
  for (int it = 0; it < 32; ++it){
    int idx = it*256 + tid;                 // 0..8191
    int ch_i = idx >> 10, rem = idx & 1023;
    int nf = rem >> 9, rem2 = rem & 511;
    int lane_i = rem2 >> 3, j = rem2 & 7;
    int gg = lane_i >> 4, ll = lane_i & 15;
    int v = 8*gg + j, w = 16*nf + ll;
    int r = rg*8 + ch_i, kg = r >> 6;
    float val = 0.f;
    if (v < cV && w < cV){
      float xv = g_x1[((size_t)n*cKM + r)*cV + v];
      float xw = g_x2[((size_t)n*cKM + r)*cV + w];
      float e = __expf(2.f*(xv - xw));
      val = __fdividef(e - 1.f, e + 1.f)*a0 + A[kg*625 + v*cV + w]
          + g_ada[((size_t)n*cK + kg)*625 + v*cV + w];
    }
    g_adF[((size_t)n*cKM + r)*1024 + rem] = f2bu(val);
  }
}

// ---------------------------------------------------------------------------
// 4) FUSED pre -> per-channel map -> out.  One block per (n, 4-t tile).
//    512 thr = 8 waves.  LDS 80 KB -> 2 blocks/CU.
//    r11: adF B-frags prefetched into regs at kg top (hidden under GEMM1);
//         GEMM3 A-frag rotation prefetch.
// ---------------------------------------------------------------------------
__global__ __launch_bounds__(512, 4) void gm_fused(const float* __restrict__ x,
                                                   float* __restrict__ outf){
  __shared__ ushort Zl[32 * 128 * 8];      // 64 KB [oct][col][j]
  __shared__ ushort Pt[256 * 4 * 8];       // 16 KB [row][g][j]
  int bid = (int)(blockIdx.x & 7) * 256 + ((int)blockIdx.x >> 3);  // XCD swizzle
  int n = bid >> 4, ttile = bid & 15;
  int t0 = ttile * 4;
  int tid = threadIdx.x;
  int wv = tid >> 6, lane = tid & 63, g = lane >> 4, l15 = lane & 15;
  int mfh = wv >> 1;          // 0..3
  int nfh = wv & 1;           // 0..1

  // ---- stage x -> Z octets 24..31 (pads zero) ----
  #pragma unroll
  for (int s0 = 0; s0 < 1024; s0 += 512){
    int s = s0 + tid;
    int oct = s >> 7, col = s & 127;
    int t = col >> 5, v = col & 31;
    ushort u[8];
    if (v < cV){
      const float* xp = x + ((size_t)n*cC + oct*8)*cTV + (t0 + t)*cV + v;
      #pragma unroll
      for (int j = 0; j < 8; ++j) u[j] = f2bu(xp[(size_t)j*cTV]);
    } else {
      #pragma unroll
      for (int j = 0; j < 8; ++j) u[j] = 0;
    }
    *(uint4*)&Zl[((24 + oct)*128 + col)*8] = *(const uint4*)u;
  }

  #pragma unroll 1
  for (int kg = 0; kg < 3; ++kg){
    __syncthreads();   // kg=0: x staged; kg>0: Pt safe to overwrite
    // ---- prefetch this kg's adF B-frags (hidden under GEMM1) ----
    s16x8 bva0[8], bva1[8];
    #pragma unroll
    for (int cc = 0; cc < 8; ++cc){
      const ushort* bp = g_adF + ((size_t)n*cKM + kg*64 + wv*8 + cc)*1024;
      bva0[cc] = *(const s16x8*)(bp + lane*8);
      bva1[cc] = *(const s16x8*)(bp + 512 + lane*8);
    }
    // ---- GEMM1: pre rows kg*64..kg*64+63, 128 cols ----
    f32x4 a1[4];
    #pragma unroll
    for (int nn = 0; nn < 4; ++nn) a1[nn] = (f32x4){0.f,0.f,0.f,0.f};
    #pragma unroll
    for (int ks = 0; ks < 2; ++ks){
      s16x8 av = *(const s16x8*)(g_WpreF + ((ks*12 + kg*4 + mfh) << 9) + lane*8);
      #pragma unroll
      for (int nn = 0; nn < 4; ++nn){
        int col = 16*(nfh*4 + nn) + l15;
        s16x8 bv = *(const s16x8*)&Zl[((24 + ks*4 + g)*128 + col)*8];
        a1[nn] = __builtin_amdgcn_mfma_f32_16x16x32_bf16(av, bv, a1[nn], 0, 0, 0);
      }
    }
    // bias+relu -> Pt (zero pads)
    #pragma unroll
    for (int nn = 0; nn < 4; ++nn){
      int col = 16*(nfh*4 + nn) + l15;
      int t = col >> 5, v = col & 31;
      #pragma unroll
      for (int q = 0; q < 4; ++q){
        int o = 16*mfh + 4*g + q;
        float val = (v < cV) ? fmaxf(a1[nn][q] + g_bpre[kg*64 + o], 0.f) : 0.f;
        Pt[((t*64 + o)*4 + (v>>3))*8 + (v&7)] = f2bu(val);
      }
    }
    __syncthreads();
    // ---- GEMM2 per channel: D[t(pad16), w] = pre[t,v] @ Adyn[v,w] ----
    #pragma unroll 2
    for (int cc = 0; cc < 8; ++cc){
      int chl = wv*8 + cc;                 // 0..63
      s16x8 av;
      if (l15 < 4) av = *(const s16x8*)&Pt[((l15*64 + chl)*4 + g)*8];
      else         av = (s16x8){0,0,0,0,0,0,0,0};
      f32x4 d0 = __builtin_amdgcn_mfma_f32_16x16x32_bf16(av, bva0[cc], (f32x4){0.f,0.f,0.f,0.f}, 0, 0, 0);
      f32x4 d1 = __builtin_amdgcn_mfma_f32_16x16x32_bf16(av, bva1[cc], (f32x4){0.f,0.f,0.f,0.f}, 0, 0, 0);
      if (g == 0){
        #pragma unroll
        for (int q = 0; q < 4; ++q){       // q = t
          Zl[((kg*8 + (chl>>3))*128 + q*32 + l15)*8 + (chl&7)] = f2bu(d0[q]);
          Zl[((kg*8 + (chl>>3))*128 + q*32 + 16 + l15)*8 + (chl&7)] = f2bu(d1[q]);
        }
      }
    }
  }
  __syncthreads();
  // ---- GEMM3: out[192][128] = Wcat[192][256] @ Z, rotated av prefetch ----
  f32x4 a3[3][4];
  #pragma unroll
  for (int mm = 0; mm < 3; ++mm)
    #pragma unroll
    for (int nn = 0; nn < 4; ++nn) a3[mm][nn] = (f32x4){0.f,0.f,0.f,0.f};
  s16x8 avc[3], avn[3];
  #pragma unroll
  for (int mm = 0; mm < 3; ++mm)
    avc[mm] = *(const s16x8*)(g_WcatF + ((0*12 + mfh*3 + mm) << 9) + lane*8);
  #pragma unroll 1
  for (int ks = 0; ks < 8; ++ks){
    if (ks < 7){
      #pragma unroll
      for (int mm = 0; mm < 3; ++mm)
        avn[mm] = *(const s16x8*)(g_WcatF + (((ks+1)*12 + mfh*3 + mm) << 9) + lane*8);
    }
    s16x8 bv[4];
    #pragma unroll
    for (int nn = 0; nn < 4; ++nn){
      int col = 16*(nfh*4 + nn) + l15;
      bv[nn] = *(const s16x8*)&Zl[((ks*4 + g)*128 + col)*8];
    }
    #pragma unroll
    for (int mm = 0; mm < 3; ++mm)
      #pragma unroll
      for (int nn = 0; nn < 4; ++nn)
        a3[mm][nn] = __builtin_amdgcn_mfma_f32_16x16x32_bf16(avc[mm], bv[nn], a3[mm][nn], 0, 0, 0);
    #pragma unroll
    for (int mm = 0; mm < 3; ++mm) avc[mm] = avn[mm];
  }
  // epilogue: bias + relu -> d_out (f32)
  #pragma unroll
  for (int mm = 0; mm < 3; ++mm){
    #pragma unroll
    for (int q = 0; q < 4; ++q){
      int o = 48*mfh + 16*mm + 4*g + q;
      float ct = g_cterm[o];
      #pragma unroll
      for (int nn = 0; nn < 4; ++nn){
        int col = 16*(nfh*4 + nn) + l15;
        int t = col >> 5, v = col & 31;
        if (v < cV)
          outf[((size_t)n*cKM + o)*cTV + (t0 + t)*cV + v] = fmaxf(a3[mm][nn][q] + ct, 0.f);
      }
    }
  }
}

// ---------------------------------------------------------------------------
extern "C" void kernel_launch(void* const* d_in, const int* in_sizes, int n_in,
                              void* d_out, int out_size, void* d_ws, size_t ws_size,
                              hipStream_t stream){
  (void)in_sizes; (void)n_in; (void)out_size; (void)d_ws; (void)ws_size;
  const float* x      = (const float*)d_in[0];
  const float* A      = (const float*)d_in[1];
  const float* alpha  = (const float*)d_in[2];
  const float* beta   = (const float*)d_in[3];
  const float* W_pre  = (const float*)d_in[4];
  const float* b_pre  = (const float*)d_in[5];
  const float* bn_pre = (const float*)d_in[6];
  const float* W1     = (const float*)d_in[7];
  const float* b1     = (const float*)d_in[8];
  const float* W2     = (const float*)d_in[9];
  const float* b2     = (const float*)d_in[10];
  const float* W_post = (const float*)d_in[11];
  const float* b_post = (const float*)d_in[12];
  const float* bn_post= (const float*)d_in[13];
  const float* W_down = (const float*)d_in[14];
  const float* b_down = (const float*)d_in[15];
  const float* bn_down= (const float*)d_in[16];
  float* out = (float*)d_out;

  k_fold  <<<1,        256, 0, stream>>>(W_pre, b_pre, bn_pre,
                                         W_post, b_post, bn_post,
                                         W_down, b_down, bn_down);
  gm_tmp  <<<cN * 16,  256, 0, stream>>>(x);
  gm_x1x2 <<<cN * 4,   256, 0, stream>>>(W1, b1, W2, b2);
  gm_ada  <<<cN * cK,  128, 0, stream>>>(beta);
  gm_adFk <<<cN * 24,  256, 0, stream>>>(A, alpha);
  gm_fused<<<cN * 16,  512, 0, stream>>>(x, out);
}

// Round 12
// 237.615 us; speedup vs baseline: 3.7870x; 3.7870x over previous
//
#include <hip/hip_runtime.h>
#include <hip/hip_bf16.h>

typedef __hip_bfloat16 bf16;
typedef __attribute__((ext_vector_type(8))) short s16x8;
typedef __attribute__((ext_vector_type(4))) float f32x4;

constexpr int cN = 128, cC = 64, cT = 64, cV = 25, cK = 3, cMID = 64, cKM = 192, cTV = 1600;
constexpr float cEPS = 1e-5f;

// BSS intermediates (no d_ws use). All rewritten before read each call.
__device__ float g_tmp[cN * cC * cV];
__device__ float g_x1 [cN * cKM * cV];
__device__ float g_x2 [cN * cKM * cV];
__device__ float g_ada[cN * cK * cV * cV];
// Per-channel Adyn in B-fragment order: [n][r][nf(2)][lane(64)][j(8)] bf16
__device__ ushort g_adF[(size_t)cN * cKM * 1024];          // 50.3 MB
// Folded weights in A-fragment order: [k-step][m-frag(12)][lane(64)][8]
__device__ ushort g_WpreF[2 * 12 * 512];
__device__ ushort g_WcatF[8 * 12 * 512];
__device__ float g_bpre [cKM];
__device__ float g_cterm[cKM];

__device__ __forceinline__ bf16  f2b(float v){ return __float2bfloat16(v); }
__device__ __forceinline__ ushort f2bu(float v){ return __builtin_bit_cast(ushort, __float2bfloat16(v)); }

// ---------------------------------------------------------------------------
// 0) fold bn into weights/biases; weights stored in A-frag order (bf16).
// ---------------------------------------------------------------------------
__global__ void k_fold(const float* __restrict__ Wpre, const float* __restrict__ bpre,
                       const float* __restrict__ bnpre,
                       const float* __restrict__ Wpost, const float* __restrict__ bpost,
                       const float* __restrict__ bnpost,
                       const float* __restrict__ Wdown, const float* __restrict__ bdown,
                       const float* __restrict__ bndown){
  __shared__ float sPre[cKM], sPost[cKM], sDown[cKM];
  int tid = threadIdx.x;
  if (tid < cKM){
    float sp = bnpre[tid] * rsqrtf(bnpre[3*cKM+tid] + cEPS);
    sPre[tid] = sp;
    g_bpre[tid] = bpre[tid]*sp + bnpre[cKM+tid] - bnpre[2*cKM+tid]*sp;
    float sP = bnpost[tid] * rsqrtf(bnpost[3*cKM+tid] + cEPS);
    float sD = bndown[tid] * rsqrtf(bndown[3*cKM+tid] + cEPS);
    sPost[tid] = sP; sDown[tid] = sD;
    g_cterm[tid] = bpost[tid]*sP + bnpost[cKM+tid] - bnpost[2*cKM+tid]*sP
                 + bdown[tid]*sD + bndown[cKM+tid] - bndown[2*cKM+tid]*sD;
  }
  __syncthreads();
  for (int idx = tid; idx < cKM*cC; idx += 256){
    int o = idx >> 6, k = idx & 63;
    int step = k >> 5, g = (k >> 3) & 3, j = k & 7;
    int dst = ((step*12 + (o>>4)) << 9) + (((g<<4) | (o&15)) << 3) + j;
    g_WpreF[dst] = f2bu(Wpre[idx] * sPre[o]);
  }
  for (int idx = tid; idx < cKM*256; idx += 256){
    int o = idx >> 8, k = idx & 255;
    float w = (k < cKM) ? Wpost[o*cKM + k] * sPost[o]
                        : Wdown[o*cC + (k - cKM)] * sDown[o];
    int step = k >> 5, g = (k >> 3) & 3, j = k & 7;
    int dst = ((step*12 + (o>>4)) << 9) + (((g<<4) | (o&15)) << 3) + j;
    g_WcatF[dst] = f2bu(w);
  }
}

// ---------------------------------------------------------------------------
// 1) g_tmp[n,c,v] = mean_t x[n,c,t,v]   coalesced via LDS.  grid = N*16.
// ---------------------------------------------------------------------------
__global__ __launch_bounds__(256) void gm_tmp(const float* __restrict__ x){
  __shared__ float xs[4 * cTV];
  int n = blockIdx.x >> 4, cg = blockIdx.x & 15;
  int tid = threadIdx.x;
  const float* xp = x + ((size_t)n*cC + cg*4)*cTV;
  for (int i = tid; i < 4*cTV; i += 256) xs[i] = xp[i];
  __syncthreads();
  if (tid < 100){
    int c = tid / 25, v = tid - c*25;
    float s = 0.f;
    #pragma unroll
    for (int t = 0; t < cT; ++t) s += xs[c*cTV + t*cV + v];
    g_tmp[(n*cC + cg*4 + c)*cV + v] = s * (1.f/cT);
  }
}

// ---------------------------------------------------------------------------
// 2) x1/x2 1x1 conv on mean
// ---------------------------------------------------------------------------
__global__ void gm_x1x2(const float* __restrict__ W1, const float* __restrict__ b1,
                        const float* __restrict__ W2, const float* __restrict__ b2){
  __shared__ float tl[cC * cV];
  __shared__ float w1[48 * cC];
  __shared__ float w2[48 * cC];
  int n = blockIdx.x >> 2, og = blockIdx.x & 3;
  int tid = threadIdx.x;
  int obase = og * 48;
  for (int i = tid; i < cC * cV; i += 256) tl[i] = g_tmp[n * cC * cV + i];
  for (int i = tid; i < 48 * cC; i += 256){
    w1[i] = W1[obase * cC + i];
    w2[i] = W2[obase * cC + i];
  }
  __syncthreads();
  for (int idx = tid; idx < 48 * cV; idx += 256){
    int j = idx / cV, v = idx % cV;
    int o = obase + j;
    float s1 = b1[o], s2 = b2[o];
    #pragma unroll
    for (int c = 0; c < cC; ++c){
      float t = tl[c * cV + v];
      s1 += w1[j * cC + c] * t;
      s2 += w2[j * cC + c] * t;
    }
    g_x1[((size_t)n * cKM + o) * cV + v] = s1;
    g_x2[((size_t)n * cKM + o) * cV + v] = s2;
  }
}

// ---------------------------------------------------------------------------
// 3) ada softmax (channel-shared part of Adyn)
// ---------------------------------------------------------------------------
__global__ void gm_ada(const float* __restrict__ beta){
  __shared__ float a1[cMID * cV];
  __shared__ float a2[cMID * cV];
  __shared__ float al[cV * cV];
  int b = blockIdx.x; int n = b / cK, k = b % cK;
  int tid = threadIdx.x;
  const float* p1 = g_x1 + ((size_t)n * cKM + k * cMID) * cV;
  const float* p2 = g_x2 + ((size_t)n * cKM + k * cMID) * cV;
  for (int i = tid; i < cMID * cV; i += 128){ a1[i] = p1[i]; a2[i] = p2[i]; }
  __syncthreads();
  for (int idx = tid; idx < cV * cV; idx += 128){
    int v = idx / cV, w = idx % cV;
    float s = 0.f;
    #pragma unroll
    for (int c = 0; c < cMID; ++c) s += a1[c * cV + v] * a2[c * cV + w];
    al[idx] = s;
  }
  __syncthreads();
  float b0 = beta[0];
  if (tid < cV){
    int w = tid;
    float m = -1e30f;
    for (int v = 0; v < cV; ++v) m = fmaxf(m, al[v * cV + w]);
    float s = 0.f;
    for (int v = 0; v < cV; ++v) s += expf(al[v * cV + w] - m);
    float inv = b0 / s;
    for (int v = 0; v < cV; ++v)
      g_ada[(size_t)b * cV * cV + v * cV + w] = expf(al[v * cV + w] - m) * inv;
  }
}

// ---------------------------------------------------------------------------
// 3b) Per-channel Adyn -> B-fragment order g_adF[n][r][nf][lane][8].
// ---------------------------------------------------------------------------
__global__ __launch_bounds__(256) void gm_adFk(const float* __restrict__ A,
                                               const float* __restrict__ alpha){
  int n = blockIdx.x / 24, rg = blockIdx.x % 24;
  int tid = threadIdx.x;
  float a0 = alpha[0];
  #pragma unroll 1
  for (int it = 0; it < 32; ++it){
    int idx = it*256 + tid;                 // 0..8191
    int ch_i = idx >> 10, rem = idx & 1023;
    int nf = rem >> 9, rem2 = rem & 511;
    int lane_i = rem2 >> 3, j = rem2 & 7;
    int gg = lane_i >> 4, ll = lane_i & 15;
    int v = 8*gg + j, w = 16*nf + ll;
    int r = rg*8 + ch_i, kg = r >> 6;
    float val = 0.f;
    if (v < cV && w < cV){
      float xv = g_x1[((size_t)n*cKM + r)*cV + v];
      float xw = g_x2[((size_t)n*cKM + r)*cV + w];
      float e = __expf(2.f*(xv - xw));
      val = __fdividef(e - 1.f, e + 1.f)*a0 + A[kg*625 + v*cV + w]
          + g_ada[((size_t)n*cK + kg)*625 + v*cV + w];
    }
    g_adF[((size_t)n*cKM + r)*1024 + rem] = f2bu(val);
  }
}

// ---------------------------------------------------------------------------
// 4) FUSED pre -> per-channel map -> out.  One block per (n, 4-t tile).
//    512 thr = 8 waves.  LDS 80 KB -> 2 blocks/CU.
//    r12: adF prefetch kept, but GEMM2 loop FULLY unrolled so bva arrays are
//    compile-time-indexed (r11's `#pragma unroll 2` sent them to scratch —
//    rule #20 — causing the 5x regression).
// ---------------------------------------------------------------------------
__global__ __launch_bounds__(512, 4) void gm_fused(const float* __restrict__ x,
                                                   float* __restrict__ outf){
  __shared__ ushort Zl[32 * 128 * 8];      // 64 KB [oct][col][j]
  __shared__ ushort Pt[256 * 4 * 8];       // 16 KB [row][g][j]
  int bid = (int)(blockIdx.x & 7) * 256 + ((int)blockIdx.x >> 3);  // XCD swizzle
  int n = bid >> 4, ttile = bid & 15;
  int t0 = ttile * 4;
  int tid = threadIdx.x;
  int wv = tid >> 6, lane = tid & 63, g = lane >> 4, l15 = lane & 15;
  int mfh = wv >> 1;          // 0..3
  int nfh = wv & 1;           // 0..1

  // ---- stage x -> Z octets 24..31 (pads zero) ----
  #pragma unroll
  for (int s0 = 0; s0 < 1024; s0 += 512){
    int s = s0 + tid;
    int oct = s >> 7, col = s & 127;
    int t = col >> 5, v = col & 31;
    ushort u[8];
    if (v < cV){
      const float* xp = x + ((size_t)n*cC + oct*8)*cTV + (t0 + t)*cV + v;
      #pragma unroll
      for (int j = 0; j < 8; ++j) u[j] = f2bu(xp[(size_t)j*cTV]);
    } else {
      #pragma unroll
      for (int j = 0; j < 8; ++j) u[j] = 0;
    }
    *(uint4*)&Zl[((24 + oct)*128 + col)*8] = *(const uint4*)u;
  }

  #pragma unroll 1
  for (int kg = 0; kg < 3; ++kg){
    __syncthreads();   // kg=0: x staged; kg>0: Pt safe to overwrite
    // ---- prefetch this kg's adF B-frags (hidden under GEMM1) ----
    // FULLY unrolled + compile-time indices everywhere -> stays in VGPRs.
    s16x8 bva0[8], bva1[8];
    #pragma unroll
    for (int cc = 0; cc < 8; ++cc){
      const ushort* bp = g_adF + ((size_t)n*cKM + kg*64 + wv*8 + cc)*1024;
      bva0[cc] = *(const s16x8*)(bp + lane*8);
      bva1[cc] = *(const s16x8*)(bp + 512 + lane*8);
    }
    // ---- GEMM1: pre rows kg*64..kg*64+63, 128 cols ----
    f32x4 a1[4];
    #pragma unroll
    for (int nn = 0; nn < 4; ++nn) a1[nn] = (f32x4){0.f,0.f,0.f,0.f};
    #pragma unroll
    for (int ks = 0; ks < 2; ++ks){
      s16x8 av = *(const s16x8*)(g_WpreF + ((ks*12 + kg*4 + mfh) << 9) + lane*8);
      #pragma unroll
      for (int nn = 0; nn < 4; ++nn){
        int col = 16*(nfh*4 + nn) + l15;
        s16x8 bv = *(const s16x8*)&Zl[((24 + ks*4 + g)*128 + col)*8];
        a1[nn] = __builtin_amdgcn_mfma_f32_16x16x32_bf16(av, bv, a1[nn], 0, 0, 0);
      }
    }
    // bias+relu -> Pt (zero pads)
    #pragma unroll
    for (int nn = 0; nn < 4; ++nn){
      int col = 16*(nfh*4 + nn) + l15;
      int t = col >> 5, v = col & 31;
      #pragma unroll
      for (int q = 0; q < 4; ++q){
        int o = 16*mfh + 4*g + q;
        float val = (v < cV) ? fmaxf(a1[nn][q] + g_bpre[kg*64 + o], 0.f) : 0.f;
        Pt[((t*64 + o)*4 + (v>>3))*8 + (v&7)] = f2bu(val);
      }
    }
    __syncthreads();
    // ---- GEMM2 per channel: D[t(pad16), w] = pre[t,v] @ Adyn[v,w] ----
    #pragma unroll
    for (int cc = 0; cc < 8; ++cc){
      int chl = wv*8 + cc;                 // 0..63
      s16x8 av;
      if (l15 < 4) av = *(const s16x8*)&Pt[((l15*64 + chl)*4 + g)*8];
      else         av = (s16x8){0,0,0,0,0,0,0,0};
      f32x4 d0 = __builtin_amdgcn_mfma_f32_16x16x32_bf16(av, bva0[cc], (f32x4){0.f,0.f,0.f,0.f}, 0, 0, 0);
      f32x4 d1 = __builtin_amdgcn_mfma_f32_16x16x32_bf16(av, bva1[cc], (f32x4){0.f,0.f,0.f,0.f}, 0, 0, 0);
      if (g == 0){
        #pragma unroll
        for (int q = 0; q < 4; ++q){       // q = t
          Zl[((kg*8 + (chl>>3))*128 + q*32 + l15)*8 + (chl&7)] = f2bu(d0[q]);
          Zl[((kg*8 + (chl>>3))*128 + q*32 + 16 + l15)*8 + (chl&7)] = f2bu(d1[q]);
        }
      }
    }
  }
  __syncthreads();
  // ---- GEMM3: out[192][128] = Wcat[192][256] @ Z, rotated av prefetch ----
  f32x4 a3[3][4];
  #pragma unroll
  for (int mm = 0; mm < 3; ++mm)
    #pragma unroll
    for (int nn = 0; nn < 4; ++nn) a3[mm][nn] = (f32x4){0.f,0.f,0.f,0.f};
  s16x8 avc[3], avn[3];
  #pragma unroll
  for (int mm = 0; mm < 3; ++mm)
    avc[mm] = *(const s16x8*)(g_WcatF + ((0*12 + mfh*3 + mm) << 9) + lane*8);
  #pragma unroll 1
  for (int ks = 0; ks < 8; ++ks){
    if (ks < 7){
      #pragma unroll
      for (int mm = 0; mm < 3; ++mm)
        avn[mm] = *(const s16x8*)(g_WcatF + (((ks+1)*12 + mfh*3 + mm) << 9) + lane*8);
    }
    s16x8 bv[4];
    #pragma unroll
    for (int nn = 0; nn < 4; ++nn){
      int col = 16*(nfh*4 + nn) + l15;
      bv[nn] = *(const s16x8*)&Zl[((ks*4 + g)*128 + col)*8];
    }
    #pragma unroll
    for (int mm = 0; mm < 3; ++mm)
      #pragma unroll
      for (int nn = 0; nn < 4; ++nn)
        a3[mm][nn] = __builtin_amdgcn_mfma_f32_16x16x32_bf16(avc[mm], bv[nn], a3[mm][nn], 0, 0, 0);
    #pragma unroll
    for (int mm = 0; mm < 3; ++mm) avc[mm] = avn[mm];
  }
  // epilogue: bias + relu -> d_out (f32)
  #pragma unroll
  for (int mm = 0; mm < 3; ++mm){
    #pragma unroll
    for (int q = 0; q < 4; ++q){
      int o = 48*mfh + 16*mm + 4*g + q;
      float ct = g_cterm[o];
      #pragma unroll
      for (int nn = 0; nn < 4; ++nn){
        int col = 16*(nfh*4 + nn) + l15;
        int t = col >> 5, v = col & 31;
        if (v < cV)
          outf[((size_t)n*cKM + o)*cTV + (t0 + t)*cV + v] = fmaxf(a3[mm][nn][q] + ct, 0.f);
      }
    }
  }
}

// ---------------------------------------------------------------------------
extern "C" void kernel_launch(void* const* d_in, const int* in_sizes, int n_in,
                              void* d_out, int out_size, void* d_ws, size_t ws_size,
                              hipStream_t stream){
  (void)in_sizes; (void)n_in; (void)out_size; (void)d_ws; (void)ws_size;
  const float* x      = (const float*)d_in[0];
  const float* A      = (const float*)d_in[1];
  const float* alpha  = (const float*)d_in[2];
  const float* beta   = (const float*)d_in[3];
  const float* W_pre  = (const float*)d_in[4];
  const float* b_pre  = (const float*)d_in[5];
  const float* bn_pre = (const float*)d_in[6];
  const float* W1     = (const float*)d_in[7];
  const float* b1     = (const float*)d_in[8];
  const float* W2     = (const float*)d_in[9];
  const float* b2     = (const float*)d_in[10];
  const float* W_post = (const float*)d_in[11];
  const float* b_post = (const float*)d_in[12];
  const float* bn_post= (const float*)d_in[13];
  const float* W_down = (const float*)d_in[14];
  const float* b_down = (const float*)d_in[15];
  const float* bn_down= (const float*)d_in[16];
  float* out = (float*)d_out;

  k_fold  <<<1,        256, 0, stream>>>(W_pre, b_pre, bn_pre,
                                         W_post, b_post, bn_post,
                                         W_down, b_down, bn_down);
  gm_tmp  <<<cN * 16,  256, 0, stream>>>(x);
  gm_x1x2 <<<cN * 4,   256, 0, stream>>>(W1, b1, W2, b2);
  gm_ada  <<<cN * cK,  128, 0, stream>>>(beta);
  gm_adFk <<<cN * 24,  256, 0, stream>>>(A, alpha);
  gm_fused<<<cN * 16,  512, 0, stream>>>(x, out);
}

// Round 13
// 191.419 us; speedup vs baseline: 4.7010x; 1.2413x over previous
//
#include <hip/hip_runtime.h>
#include <hip/hip_bf16.h>

typedef __hip_bfloat16 bf16;
typedef __attribute__((ext_vector_type(8))) short s16x8;
typedef __attribute__((ext_vector_type(4))) float f32x4;

constexpr int cN = 128, cC = 64, cT = 64, cV = 25, cK = 3, cMID = 64, cKM = 192, cTV = 1600;
constexpr float cEPS = 1e-5f;

// BSS intermediates (no d_ws use). All rewritten before read each call.
__device__ float g_tmp[cN * cC * cV];
// Per-channel Adyn in B-fragment order: [n][r][nf(2)][lane(64)][j(8)] bf16
__device__ ushort g_adF[(size_t)cN * cKM * 1024];          // 50.3 MB
// Folded weights in A-fragment order: [k-step][m-frag(12)][lane(64)][8]
__device__ ushort g_WpreF[2 * 12 * 512];
__device__ ushort g_WcatF[8 * 12 * 512];
__device__ float g_bpre [cKM];
__device__ float g_cterm[cKM];

__device__ __forceinline__ ushort f2bu(float v){ return __builtin_bit_cast(ushort, __float2bfloat16(v)); }

// ---------------------------------------------------------------------------
// 0) fold bn into weights/biases; A-frag order (bf16).  grid = 8 (24 o's each).
// ---------------------------------------------------------------------------
__global__ __launch_bounds__(256) void k_fold(
    const float* __restrict__ Wpre, const float* __restrict__ bpre,
    const float* __restrict__ bnpre,
    const float* __restrict__ Wpost, const float* __restrict__ bpost,
    const float* __restrict__ bnpost,
    const float* __restrict__ Wdown, const float* __restrict__ bdown,
    const float* __restrict__ bndown){
  __shared__ float sPre[24], sPost[24], sDown[24];
  int ob = blockIdx.x * 24;
  int tid = threadIdx.x;
  if (tid < 24){
    int o = ob + tid;
    float sp = bnpre[o] * rsqrtf(bnpre[3*cKM+o] + cEPS);
    sPre[tid] = sp;
    g_bpre[o] = bpre[o]*sp + bnpre[cKM+o] - bnpre[2*cKM+o]*sp;
    float sP = bnpost[o] * rsqrtf(bnpost[3*cKM+o] + cEPS);
    float sD = bndown[o] * rsqrtf(bndown[3*cKM+o] + cEPS);
    sPost[tid] = sP; sDown[tid] = sD;
    g_cterm[o] = bpost[o]*sP + bnpost[cKM+o] - bnpost[2*cKM+o]*sP
               + bdown[o]*sD + bndown[cKM+o] - bndown[2*cKM+o]*sD;
  }
  __syncthreads();
  for (int i = tid; i < 24*cC; i += 256){
    int ol = i >> 6, k = i & 63;
    int o = ob + ol;
    int step = k >> 5, g = (k >> 3) & 3, j = k & 7;
    int dst = ((step*12 + (o>>4)) << 9) + (((g<<4) | (o&15)) << 3) + j;
    g_WpreF[dst] = f2bu(Wpre[o*cC + k] * sPre[ol]);
  }
  for (int i = tid; i < 24*256; i += 256){
    int ol = i >> 8, k = i & 255;
    int o = ob + ol;
    float w = (k < cKM) ? Wpost[o*cKM + k] * sPost[ol]
                        : Wdown[o*cC + (k - cKM)] * sDown[ol];
    int step = k >> 5, g = (k >> 3) & 3, j = k & 7;
    int dst = ((step*12 + (o>>4)) << 9) + (((g<<4) | (o&15)) << 3) + j;
    g_WcatF[dst] = f2bu(w);
  }
}

// ---------------------------------------------------------------------------
// 1) g_tmp[n,c,v] = mean_t x[n,c,t,v]   coalesced via LDS.  grid = N*16.
// ---------------------------------------------------------------------------
__global__ __launch_bounds__(256) void gm_tmp(const float* __restrict__ x){
  __shared__ float xs[4 * cTV];
  int n = blockIdx.x >> 4, cg = blockIdx.x & 15;
  int tid = threadIdx.x;
  const float* xp = x + ((size_t)n*cC + cg*4)*cTV;
  for (int i = tid; i < 4*cTV; i += 256) xs[i] = xp[i];
  __syncthreads();
  if (tid < 100){
    int c = tid / 25, v = tid - c*25;
    float s = 0.f;
    #pragma unroll
    for (int t = 0; t < cT; ++t) s += xs[c*cTV + t*cV + v];
    g_tmp[(n*cC + cg*4 + c)*cV + v] = s * (1.f/cT);
  }
}

// ---------------------------------------------------------------------------
// 2) PREP (replaces x1x2 + ada + adFk): everything after tmp is (n,kg)-local.
//    grid = N*3, 256 thr.  Writes ONLY g_adF (paired u32, coalesced).
// ---------------------------------------------------------------------------
__global__ __launch_bounds__(256) void gm_prep(
    const float* __restrict__ W1, const float* __restrict__ b1,
    const float* __restrict__ W2, const float* __restrict__ b2,
    const float* __restrict__ A,  const float* __restrict__ alpha,
    const float* __restrict__ beta){
  __shared__ float tl [cC*cV];     // tmp slice      6.4 KB
  __shared__ float x1l[cMID*cV];   // [ch][v]        6.4 KB
  __shared__ float x2l[cMID*cV];
  __shared__ float adal[cV*cV];    // gram -> softmax 2.5 KB
  __shared__ float Al [cV*cV];
  int bid = blockIdx.x; int n = bid / 3, kg = bid % 3;
  int tid = threadIdx.x;
  for (int i = tid; i < cC*cV; i += 256) tl[i] = g_tmp[n*cC*cV + i];
  for (int i = tid; i < cV*cV; i += 256) Al[i] = A[kg*625 + i];
  __syncthreads();
  // x1/x2 = W@tmp + b  (weights L1/L2-hot: 2x16KB slice)
  for (int idx = tid; idx < cMID*cV; idx += 256){
    int ch = idx / cV, v = idx % cV;
    int o = kg*cMID + ch;
    float s1 = b1[o], s2 = b2[o];
    const float* w1p = W1 + o*cC;
    const float* w2p = W2 + o*cC;
    #pragma unroll 8
    for (int c = 0; c < cC; ++c){
      float t = tl[c*cV + v];
      s1 += w1p[c]*t; s2 += w2p[c]*t;
    }
    x1l[idx] = s1; x2l[idx] = s2;
  }
  __syncthreads();
  // gram scores s[v][w]
  for (int idx = tid; idx < cV*cV; idx += 256){
    int v = idx / cV, w = idx % cV;
    float s = 0.f;
    #pragma unroll 8
    for (int c = 0; c < cMID; ++c) s += x1l[c*cV + v] * x2l[c*cV + w];
    adal[idx] = s;
  }
  __syncthreads();
  // softmax over v (axis -2), scaled by beta[0]
  float b0 = beta[0];
  if (tid < cV){
    int w = tid;
    float m = -1e30f;
    for (int v = 0; v < cV; ++v) m = fmaxf(m, adal[v*cV + w]);
    float s = 0.f;
    for (int v = 0; v < cV; ++v) s += __expf(adal[v*cV + w] - m);
    float inv = b0 / s;
    for (int v = 0; v < cV; ++v) adal[v*cV + w] = __expf(adal[v*cV + w] - m) * inv;
  }
  __syncthreads();
  // adF assembly: 64 ch x 1024 frag entries, paired u32 writes
  float a0 = alpha[0];
  ushort* dst = g_adF + ((size_t)n*cKM + kg*cMID) * 1024;
  #pragma unroll 1
  for (int e0 = 0; e0 < 65536; e0 += 512){
    int e = e0 + tid*2;
    int ch = e >> 10, rem = e & 1023;
    int nf = rem >> 9, r2 = rem & 511;
    int li = r2 >> 3, j0 = r2 & 7;          // j0 even
    int v0 = 8*(li >> 4) + j0, w = 16*nf + (li & 15);
    float f0 = 0.f, f1 = 0.f;
    if (w < cV){
      float xw = x2l[ch*cV + w];
      float shared = Al[0];  // dummy to keep shape; replaced below
      (void)shared;
      if (v0 < cV){
        float e2 = __expf(2.f*(x1l[ch*cV + v0] - xw));
        f0 = __fdividef(e2-1.f, e2+1.f)*a0 + Al[v0*cV + w] + adal[v0*cV + w];
      }
      if (v0 + 1 < cV){
        float e2 = __expf(2.f*(x1l[ch*cV + v0+1] - xw));
        f1 = __fdividef(e2-1.f, e2+1.f)*a0 + Al[(v0+1)*cV + w] + adal[(v0+1)*cV + w];
      }
    }
    uint pk = (uint)f2bu(f0) | ((uint)f2bu(f1) << 16);
    *(uint*)&dst[e] = pk;
  }
}

// ---------------------------------------------------------------------------
// 3) FUSED pre -> per-channel map -> out.  One block per (n, 4-t tile).
//    512 thr = 8 waves.  LDS 80 KB -> 2 blocks/CU.
//    r13: Pt re-laid as [chl][slot^swz][t][8] -> conflict-free GEMM2 reads.
// ---------------------------------------------------------------------------
__global__ __launch_bounds__(512, 4) void gm_fused(const float* __restrict__ x,
                                                   float* __restrict__ outf){
  __shared__ ushort Zl[32 * 128 * 8];      // 64 KB [oct][col][j]
  __shared__ ushort Pt[64 * 128];          // 16 KB [chl][slot][t][8]
  int bid = (int)(blockIdx.x & 7) * 256 + ((int)blockIdx.x >> 3);  // XCD swizzle
  int n = bid >> 4, ttile = bid & 15;
  int t0 = ttile * 4;
  int tid = threadIdx.x;
  int wv = tid >> 6, lane = tid & 63, g = lane >> 4, l15 = lane & 15;
  int mfh = wv >> 1;          // 0..3
  int nfh = wv & 1;           // 0..1

  // ---- stage x -> Z octets 24..31 (pads zero) ----
  #pragma unroll
  for (int s0 = 0; s0 < 1024; s0 += 512){
    int s = s0 + tid;
    int oct = s >> 7, col = s & 127;
    int t = col >> 5, v = col & 31;
    ushort u[8];
    if (v < cV){
      const float* xp = x + ((size_t)n*cC + oct*8)*cTV + (t0 + t)*cV + v;
      #pragma unroll
      for (int j = 0; j < 8; ++j) u[j] = f2bu(xp[(size_t)j*cTV]);
    } else {
      #pragma unroll
      for (int j = 0; j < 8; ++j) u[j] = 0;
    }
    *(uint4*)&Zl[((24 + oct)*128 + col)*8] = *(const uint4*)u;
  }

  #pragma unroll 1
  for (int kg = 0; kg < 3; ++kg){
    __syncthreads();   // kg=0: x staged; kg>0: Pt safe to overwrite
    // ---- prefetch this kg's adF B-frags (hidden under GEMM1) ----
    s16x8 bva0[8], bva1[8];
    #pragma unroll
    for (int cc = 0; cc < 8; ++cc){
      const ushort* bp = g_adF + ((size_t)n*cKM + kg*64 + wv*8 + cc)*1024;
      bva0[cc] = *(const s16x8*)(bp + lane*8);
      bva1[cc] = *(const s16x8*)(bp + 512 + lane*8);
    }
    // ---- GEMM1: pre rows kg*64..kg*64+63, 128 cols ----
    f32x4 a1[4];
    #pragma unroll
    for (int nn = 0; nn < 4; ++nn) a1[nn] = (f32x4){0.f,0.f,0.f,0.f};
    #pragma unroll
    for (int ks = 0; ks < 2; ++ks){
      s16x8 av = *(const s16x8*)(g_WpreF + ((ks*12 + kg*4 + mfh) << 9) + lane*8);
      #pragma unroll
      for (int nn = 0; nn < 4; ++nn){
        int col = 16*(nfh*4 + nn) + l15;
        s16x8 bv = *(const s16x8*)&Zl[((24 + ks*4 + g)*128 + col)*8];
        a1[nn] = __builtin_amdgcn_mfma_f32_16x16x32_bf16(av, bv, a1[nn], 0, 0, 0);
      }
    }
    // bias+relu -> Pt (zero pads), XOR-swizzled slot
    #pragma unroll
    for (int nn = 0; nn < 4; ++nn){
      int col = 16*(nfh*4 + nn) + l15;
      int t = col >> 5, v = col & 31;
      #pragma unroll
      for (int q = 0; q < 4; ++q){
        int o = 16*mfh + 4*g + q;
        float val = (v < cV) ? fmaxf(a1[nn][q] + g_bpre[kg*64 + o], 0.f) : 0.f;
        int slot = ((v>>3) ^ (o>>2)) & 3;
        Pt[o*128 + slot*32 + t*8 + (v & 7)] = f2bu(val);
      }
    }
    __syncthreads();
    // ---- GEMM2 per channel: D[t(pad16), w] = pre[t,v] @ Adyn[v,w] ----
    #pragma unroll
    for (int cc = 0; cc < 8; ++cc){
      int chl = wv*8 + cc;                 // 0..63
      s16x8 av;
      if (l15 < 4){
        int slot = (g ^ (chl>>2)) & 3;
        av = *(const s16x8*)&Pt[chl*128 + slot*32 + l15*8];
      } else av = (s16x8){0,0,0,0,0,0,0,0};
      f32x4 d0 = __builtin_amdgcn_mfma_f32_16x16x32_bf16(av, bva0[cc], (f32x4){0.f,0.f,0.f,0.f}, 0, 0, 0);
      f32x4 d1 = __builtin_amdgcn_mfma_f32_16x16x32_bf16(av, bva1[cc], (f32x4){0.f,0.f,0.f,0.f}, 0, 0, 0);
      if (g == 0){
        #pragma unroll
        for (int q = 0; q < 4; ++q){       // q = t
          Zl[((kg*8 + (chl>>3))*128 + q*32 + l15)*8 + (chl&7)] = f2bu(d0[q]);
          Zl[((kg*8 + (chl>>3))*128 + q*32 + 16 + l15)*8 + (chl&7)] = f2bu(d1[q]);
        }
      }
    }
  }
  __syncthreads();
  // ---- GEMM3: out[192][128] = Wcat[192][256] @ Z, rotated av prefetch ----
  f32x4 a3[3][4];
  #pragma unroll
  for (int mm = 0; mm < 3; ++mm)
    #pragma unroll
    for (int nn = 0; nn < 4; ++nn) a3[mm][nn] = (f32x4){0.f,0.f,0.f,0.f};
  s16x8 avc[3], avn[3];
  #pragma unroll
  for (int mm = 0; mm < 3; ++mm)
    avc[mm] = *(const s16x8*)(g_WcatF + ((0*12 + mfh*3 + mm) << 9) + lane*8);
  #pragma unroll 1
  for (int ks = 0; ks < 8; ++ks){
    if (ks < 7){
      #pragma unroll
      for (int mm = 0; mm < 3; ++mm)
        avn[mm] = *(const s16x8*)(g_WcatF + (((ks+1)*12 + mfh*3 + mm) << 9) + lane*8);
    }
    s16x8 bv[4];
    #pragma unroll
    for (int nn = 0; nn < 4; ++nn){
      int col = 16*(nfh*4 + nn) + l15;
      bv[nn] = *(const s16x8*)&Zl[((ks*4 + g)*128 + col)*8];
    }
    #pragma unroll
    for (int mm = 0; mm < 3; ++mm)
      #pragma unroll
      for (int nn = 0; nn < 4; ++nn)
        a3[mm][nn] = __builtin_amdgcn_mfma_f32_16x16x32_bf16(avc[mm], bv[nn], a3[mm][nn], 0, 0, 0);
    #pragma unroll
    for (int mm = 0; mm < 3; ++mm) avc[mm] = avn[mm];
  }
  // epilogue: bias + relu -> d_out (f32)
  #pragma unroll
  for (int mm = 0; mm < 3; ++mm){
    #pragma unroll
    for (int q = 0; q < 4; ++q){
      int o = 48*mfh + 16*mm + 4*g + q;
      float ct = g_cterm[o];
      #pragma unroll
      for (int nn = 0; nn < 4; ++nn){
        int col = 16*(nfh*4 + nn) + l15;
        int t = col >> 5, v = col & 31;
        if (v < cV)
          outf[((size_t)n*cKM + o)*cTV + (t0 + t)*cV + v] = fmaxf(a3[mm][nn][q] + ct, 0.f);
      }
    }
  }
}

// ---------------------------------------------------------------------------
extern "C" void kernel_launch(void* const* d_in, const int* in_sizes, int n_in,
                              void* d_out, int out_size, void* d_ws, size_t ws_size,
                              hipStream_t stream){
  (void)in_sizes; (void)n_in; (void)out_size; (void)d_ws; (void)ws_size;
  const float* x      = (const float*)d_in[0];
  const float* A      = (const float*)d_in[1];
  const float* alpha  = (const float*)d_in[2];
  const float* beta   = (const float*)d_in[3];
  const float* W_pre  = (const float*)d_in[4];
  const float* b_pre  = (const float*)d_in[5];
  const float* bn_pre = (const float*)d_in[6];
  const float* W1     = (const float*)d_in[7];
  const float* b1     = (const float*)d_in[8];
  const float* W2     = (const float*)d_in[9];
  const float* b2     = (const float*)d_in[10];
  const float* W_post = (const float*)d_in[11];
  const float* b_post = (const float*)d_in[12];
  const float* bn_post= (const float*)d_in[13];
  const float* W_down = (const float*)d_in[14];
  const float* b_down = (const float*)d_in[15];
  const float* bn_down= (const float*)d_in[16];
  float* out = (float*)d_out;

  k_fold  <<<8,        256, 0, stream>>>(W_pre, b_pre, bn_pre,
                                         W_post, b_post, bn_post,
                                         W_down, b_down, bn_down);
  gm_tmp  <<<cN * 16,  256, 0, stream>>>(x);
  gm_prep <<<cN * 3,   256, 0, stream>>>(W1, b1, W2, b2, A, alpha, beta);
  gm_fused<<<cN * 16,  512, 0, stream>>>(x, out);
}

// Round 14
// 163.899 us; speedup vs baseline: 5.4903x; 1.1679x over previous
//
#include <hip/hip_runtime.h>
#include <hip/hip_bf16.h>

typedef __hip_bfloat16 bf16;
typedef __attribute__((ext_vector_type(8))) short s16x8;
typedef __attribute__((ext_vector_type(4))) float f32x4;

constexpr int cN = 128, cC = 64, cT = 64, cV = 25, cK = 3, cMID = 64, cKM = 192, cTV = 1600;
constexpr float cEPS = 1e-5f;

// BSS intermediates (no d_ws use). All rewritten before read each call.
__device__ float g_tmp[cN * cC * cV];
// Per-channel Adyn in B-fragment order: [n][r][nf(2)][lane(64)][j(8)] bf16
__device__ ushort g_adF[(size_t)cN * cKM * 1024];          // 50.3 MB
// Folded weights in A-fragment order: [k-step][m-frag(12)][lane(64)][8]
__device__ ushort g_WpreF[2 * 12 * 512];
__device__ ushort g_WcatF[8 * 12 * 512];
__device__ float g_bpre [cKM];
__device__ float g_cterm[cKM];

__device__ __forceinline__ ushort f2bu(float v){ return __builtin_bit_cast(ushort, __float2bfloat16(v)); }

// ---------------------------------------------------------------------------
// 1) g_tmp[n,c,v] = mean_t x[n,c,t,v]  (grid = N*16) + blocks 0..7 also fold
//    bn into weights/biases (A-frag order) as a side job.
// ---------------------------------------------------------------------------
__global__ __launch_bounds__(256) void gm_tmp(const float* __restrict__ x,
    const float* __restrict__ Wpre, const float* __restrict__ bpre,
    const float* __restrict__ bnpre,
    const float* __restrict__ Wpost, const float* __restrict__ bpost,
    const float* __restrict__ bnpost,
    const float* __restrict__ Wdown, const float* __restrict__ bdown,
    const float* __restrict__ bndown){
  __shared__ float xs[4 * cTV];
  int n = blockIdx.x >> 4, cg = blockIdx.x & 15;
  int tid = threadIdx.x;
  const float* xp = x + ((size_t)n*cC + cg*4)*cTV;
  for (int i = tid; i < 4*cTV; i += 256) xs[i] = xp[i];
  __syncthreads();
  if (tid < 100){
    int c = tid / 25, v = tid - c*25;
    float s = 0.f;
    #pragma unroll
    for (int t = 0; t < cT; ++t) s += xs[c*cTV + t*cV + v];
    g_tmp[(n*cC + cg*4 + c)*cV + v] = s * (1.f/cT);
  }
  // ---- fold side-job on blocks 0..7 (24 o's each) ----
  if (blockIdx.x >= 8) return;
  __syncthreads();                    // xs reuse
  float* sPre  = xs;
  float* sPost = xs + 32;
  float* sDown = xs + 64;
  int ob = blockIdx.x * 24;
  if (tid < 24){
    int o = ob + tid;
    float sp = bnpre[o] * rsqrtf(bnpre[3*cKM+o] + cEPS);
    sPre[tid] = sp;
    g_bpre[o] = bpre[o]*sp + bnpre[cKM+o] - bnpre[2*cKM+o]*sp;
    float sP = bnpost[o] * rsqrtf(bnpost[3*cKM+o] + cEPS);
    float sD = bndown[o] * rsqrtf(bndown[3*cKM+o] + cEPS);
    sPost[tid] = sP; sDown[tid] = sD;
    g_cterm[o] = bpost[o]*sP + bnpost[cKM+o] - bnpost[2*cKM+o]*sP
               + bdown[o]*sD + bndown[cKM+o] - bndown[2*cKM+o]*sD;
  }
  __syncthreads();
  for (int i = tid; i < 24*cC; i += 256){
    int ol = i >> 6, k = i & 63;
    int o = ob + ol;
    int step = k >> 5, g = (k >> 3) & 3, j = k & 7;
    int dst = ((step*12 + (o>>4)) << 9) + (((g<<4) | (o&15)) << 3) + j;
    g_WpreF[dst] = f2bu(Wpre[o*cC + k] * sPre[ol]);
  }
  for (int i = tid; i < 24*256; i += 256){
    int ol = i >> 8, k = i & 255;
    int o = ob + ol;
    float w = (k < cKM) ? Wpost[o*cKM + k] * sPost[ol]
                        : Wdown[o*cC + (k - cKM)] * sDown[ol];
    int step = k >> 5, g = (k >> 3) & 3, j = k & 7;
    int dst = ((step*12 + (o>>4)) << 9) + (((g<<4) | (o&15)) << 3) + j;
    g_WcatF[dst] = f2bu(w);
  }
}

// ---------------------------------------------------------------------------
// 2) PREP: x1x2 -> gram -> softmax -> adF assembly.  grid = N*3, 512 thr.
//    r14: 512 thr; W slices in LDS (row-padded 65); assembly with hoisted
//    per-thread indices + pre-summed (A + ada); coalesced paired-u32 stores.
// ---------------------------------------------------------------------------
__global__ __launch_bounds__(512) void gm_prep(
    const float* __restrict__ W1, const float* __restrict__ b1,
    const float* __restrict__ W2, const float* __restrict__ b2,
    const float* __restrict__ A,  const float* __restrict__ alpha,
    const float* __restrict__ beta){
  __shared__ float tl [cC*cV + 32];   // tmp slice (+pad: reads up to v=31)
  __shared__ float w1l[cMID*65];      // 16.6 KB, row-padded -> conflict-free
  __shared__ float w2l[cMID*65];
  __shared__ float x1l[cMID*cV];
  __shared__ float x2l[cMID*cV];
  __shared__ float Al [cV*cV];        // A, later A + ada
  __shared__ float adal[cV*cV];
  int bid = blockIdx.x; int n = bid / 3, kg = bid % 3;
  int tid = threadIdx.x;
  // ---- stage tmp slice, A, W1/W2 slices ----
  for (int i = tid; i < cC*cV; i += 512) tl[i] = g_tmp[n*cC*cV + i];
  if (tid < 32) tl[cC*cV + tid] = 0.f;
  for (int i = tid; i < cV*cV; i += 512) Al[i] = A[kg*625 + i];
  for (int i = tid; i < cMID*cC; i += 512){
    int ch = i >> 6, c = i & 63;
    w1l[ch*65 + c] = W1[(kg*cMID + ch)*cC + c];
    w2l[ch*65 + c] = W2[(kg*cMID + ch)*cC + c];
  }
  __syncthreads();
  // ---- x1/x2: 8 threads per channel, 4 v's each (v = iv + 8k) ----
  {
    int ch = tid >> 3, iv = tid & 7;
    int o = kg*cMID + ch;
    float bb1 = b1[o], bb2 = b2[o];
    float s1[4] = {bb1, bb1, bb1, bb1};
    float s2[4] = {bb2, bb2, bb2, bb2};
    #pragma unroll 8
    for (int c = 0; c < cC; ++c){
      float w1c = w1l[ch*65 + c], w2c = w2l[ch*65 + c];
      #pragma unroll
      for (int k = 0; k < 4; ++k){
        float t = tl[c*cV + iv + 8*k];       // padded reads for v>=25 give 0
        s1[k] += w1c * t;
        s2[k] += w2c * t;
      }
    }
    #pragma unroll
    for (int k = 0; k < 4; ++k){
      int v = iv + 8*k;
      if (v < cV){ x1l[ch*cV + v] = s1[k]; x2l[ch*cV + v] = s2[k]; }
    }
  }
  __syncthreads();
  // ---- gram scores s[v][w] ----
  for (int idx = tid; idx < cV*cV; idx += 512){
    int v = idx / cV, w = idx % cV;
    float s = 0.f;
    #pragma unroll 8
    for (int c = 0; c < cMID; ++c) s += x1l[c*cV + v] * x2l[c*cV + w];
    adal[idx] = s;
  }
  __syncthreads();
  // ---- softmax over v (axis -2), scaled by beta[0] ----
  float b0 = beta[0];
  if (tid < cV){
    int w = tid;
    float m = -1e30f;
    for (int v = 0; v < cV; ++v) m = fmaxf(m, adal[v*cV + w]);
    float s = 0.f;
    for (int v = 0; v < cV; ++v) s += __expf(adal[v*cV + w] - m);
    float inv = b0 / s;
    for (int v = 0; v < cV; ++v) adal[v*cV + w] = __expf(adal[v*cV + w] - m) * inv;
  }
  __syncthreads();
  // ---- Al := A + ada (saves one LDS read per assembly element) ----
  for (int i = tid; i < cV*cV; i += 512) Al[i] += adal[i];
  __syncthreads();
  // ---- adF assembly: per-thread indices hoisted; loop over 64 channels ----
  float a0 = alpha[0];
  int rem = tid * 2;                       // 0..1022, even
  int nf = rem >> 9, r2 = rem & 511;
  int li = r2 >> 3, j0 = r2 & 7;
  int v0 = 8*(li >> 4) + j0, w = 16*nf + (li & 15);
  bool wok = (w < cV);
  bool v0ok = wok && (v0 < cV), v1ok = wok && (v0 + 1 < cV);
  float AW0 = v0ok ? Al[v0*cV + w] : 0.f;
  float AW1 = v1ok ? Al[(v0+1)*cV + w] : 0.f;
  uint* dst = (uint*)(g_adF + ((size_t)n*cKM + kg*cMID)*1024 + rem);
  #pragma unroll 4
  for (int ch = 0; ch < cMID; ++ch){
    float f0 = 0.f, f1 = 0.f;
    if (wok){
      float xw = x2l[ch*cV + w];
      if (v0ok){
        float e2 = __expf(2.f*(x1l[ch*cV + v0] - xw));
        f0 = __fdividef(e2 - 1.f, e2 + 1.f)*a0 + AW0;
      }
      if (v1ok){
        float e2 = __expf(2.f*(x1l[ch*cV + v0 + 1] - xw));
        f1 = __fdividef(e2 - 1.f, e2 + 1.f)*a0 + AW1;
      }
    }
    dst[(size_t)ch * 512] = (uint)f2bu(f0) | ((uint)f2bu(f1) << 16);
  }
}

// ---------------------------------------------------------------------------
// 3) FUSED pre -> per-channel map -> out.  One block per (n, 4-t tile).
//    512 thr = 8 waves.  LDS 80 KB -> 2 blocks/CU.   (unchanged from r13)
// ---------------------------------------------------------------------------
__global__ __launch_bounds__(512, 4) void gm_fused(const float* __restrict__ x,
                                                   float* __restrict__ outf){
  __shared__ ushort Zl[32 * 128 * 8];      // 64 KB [oct][col][j]
  __shared__ ushort Pt[64 * 128];          // 16 KB [chl][slot][t][8]
  int bid = (int)(blockIdx.x & 7) * 256 + ((int)blockIdx.x >> 3);  // XCD swizzle
  int n = bid >> 4, ttile = bid & 15;
  int t0 = ttile * 4;
  int tid = threadIdx.x;
  int wv = tid >> 6, lane = tid & 63, g = lane >> 4, l15 = lane & 15;
  int mfh = wv >> 1;          // 0..3
  int nfh = wv & 1;           // 0..1

  // ---- stage x -> Z octets 24..31 (pads zero) ----
  #pragma unroll
  for (int s0 = 0; s0 < 1024; s0 += 512){
    int s = s0 + tid;
    int oct = s >> 7, col = s & 127;
    int t = col >> 5, v = col & 31;
    ushort u[8];
    if (v < cV){
      const float* xp = x + ((size_t)n*cC + oct*8)*cTV + (t0 + t)*cV + v;
      #pragma unroll
      for (int j = 0; j < 8; ++j) u[j] = f2bu(xp[(size_t)j*cTV]);
    } else {
      #pragma unroll
      for (int j = 0; j < 8; ++j) u[j] = 0;
    }
    *(uint4*)&Zl[((24 + oct)*128 + col)*8] = *(const uint4*)u;
  }

  #pragma unroll 1
  for (int kg = 0; kg < 3; ++kg){
    __syncthreads();   // kg=0: x staged; kg>0: Pt safe to overwrite
    // ---- prefetch this kg's adF B-frags (hidden under GEMM1) ----
    s16x8 bva0[8], bva1[8];
    #pragma unroll
    for (int cc = 0; cc < 8; ++cc){
      const ushort* bp = g_adF + ((size_t)n*cKM + kg*64 + wv*8 + cc)*1024;
      bva0[cc] = *(const s16x8*)(bp + lane*8);
      bva1[cc] = *(const s16x8*)(bp + 512 + lane*8);
    }
    // ---- GEMM1: pre rows kg*64..kg*64+63, 128 cols ----
    f32x4 a1[4];
    #pragma unroll
    for (int nn = 0; nn < 4; ++nn) a1[nn] = (f32x4){0.f,0.f,0.f,0.f};
    #pragma unroll
    for (int ks = 0; ks < 2; ++ks){
      s16x8 av = *(const s16x8*)(g_WpreF + ((ks*12 + kg*4 + mfh) << 9) + lane*8);
      #pragma unroll
      for (int nn = 0; nn < 4; ++nn){
        int col = 16*(nfh*4 + nn) + l15;
        s16x8 bv = *(const s16x8*)&Zl[((24 + ks*4 + g)*128 + col)*8];
        a1[nn] = __builtin_amdgcn_mfma_f32_16x16x32_bf16(av, bv, a1[nn], 0, 0, 0);
      }
    }
    // bias+relu -> Pt (zero pads), XOR-swizzled slot
    #pragma unroll
    for (int nn = 0; nn < 4; ++nn){
      int col = 16*(nfh*4 + nn) + l15;
      int t = col >> 5, v = col & 31;
      #pragma unroll
      for (int q = 0; q < 4; ++q){
        int o = 16*mfh + 4*g + q;
        float val = (v < cV) ? fmaxf(a1[nn][q] + g_bpre[kg*64 + o], 0.f) : 0.f;
        int slot = ((v>>3) ^ (o>>2)) & 3;
        Pt[o*128 + slot*32 + t*8 + (v & 7)] = f2bu(val);
      }
    }
    __syncthreads();
    // ---- GEMM2 per channel: D[t(pad16), w] = pre[t,v] @ Adyn[v,w] ----
    #pragma unroll
    for (int cc = 0; cc < 8; ++cc){
      int chl = wv*8 + cc;                 // 0..63
      s16x8 av;
      if (l15 < 4){
        int slot = (g ^ (chl>>2)) & 3;
        av = *(const s16x8*)&Pt[chl*128 + slot*32 + l15*8];
      } else av = (s16x8){0,0,0,0,0,0,0,0};
      f32x4 d0 = __builtin_amdgcn_mfma_f32_16x16x32_bf16(av, bva0[cc], (f32x4){0.f,0.f,0.f,0.f}, 0, 0, 0);
      f32x4 d1 = __builtin_amdgcn_mfma_f32_16x16x32_bf16(av, bva1[cc], (f32x4){0.f,0.f,0.f,0.f}, 0, 0, 0);
      if (g == 0){
        #pragma unroll
        for (int q = 0; q < 4; ++q){       // q = t
          Zl[((kg*8 + (chl>>3))*128 + q*32 + l15)*8 + (chl&7)] = f2bu(d0[q]);
          Zl[((kg*8 + (chl>>3))*128 + q*32 + 16 + l15)*8 + (chl&7)] = f2bu(d1[q]);
        }
      }
    }
  }
  __syncthreads();
  // ---- GEMM3: out[192][128] = Wcat[192][256] @ Z, rotated av prefetch ----
  f32x4 a3[3][4];
  #pragma unroll
  for (int mm = 0; mm < 3; ++mm)
    #pragma unroll
    for (int nn = 0; nn < 4; ++nn) a3[mm][nn] = (f32x4){0.f,0.f,0.f,0.f};
  s16x8 avc[3], avn[3];
  #pragma unroll
  for (int mm = 0; mm < 3; ++mm)
    avc[mm] = *(const s16x8*)(g_WcatF + ((0*12 + mfh*3 + mm) << 9) + lane*8);
  #pragma unroll 1
  for (int ks = 0; ks < 8; ++ks){
    if (ks < 7){
      #pragma unroll
      for (int mm = 0; mm < 3; ++mm)
        avn[mm] = *(const s16x8*)(g_WcatF + (((ks+1)*12 + mfh*3 + mm) << 9) + lane*8);
    }
    s16x8 bv[4];
    #pragma unroll
    for (int nn = 0; nn < 4; ++nn){
      int col = 16*(nfh*4 + nn) + l15;
      bv[nn] = *(const s16x8*)&Zl[((ks*4 + g)*128 + col)*8];
    }
    #pragma unroll
    for (int mm = 0; mm < 3; ++mm)
      #pragma unroll
      for (int nn = 0; nn < 4; ++nn)
        a3[mm][nn] = __builtin_amdgcn_mfma_f32_16x16x32_bf16(avc[mm], bv[nn], a3[mm][nn], 0, 0, 0);
    #pragma unroll
    for (int mm = 0; mm < 3; ++mm) avc[mm] = avn[mm];
  }
  // epilogue: bias + relu -> d_out (f32)
  #pragma unroll
  for (int mm = 0; mm < 3; ++mm){
    #pragma unroll
    for (int q = 0; q < 4; ++q){
      int o = 48*mfh + 16*mm + 4*g + q;
      float ct = g_cterm[o];
      #pragma unroll
      for (int nn = 0; nn < 4; ++nn){
        int col = 16*(nfh*4 + nn) + l15;
        int t = col >> 5, v = col & 31;
        if (v < cV)
          outf[((size_t)n*cKM + o)*cTV + (t0 + t)*cV + v] = fmaxf(a3[mm][nn][q] + ct, 0.f);
      }
    }
  }
}

// ---------------------------------------------------------------------------
extern "C" void kernel_launch(void* const* d_in, const int* in_sizes, int n_in,
                              void* d_out, int out_size, void* d_ws, size_t ws_size,
                              hipStream_t stream){
  (void)in_sizes; (void)n_in; (void)out_size; (void)d_ws; (void)ws_size;
  const float* x      = (const float*)d_in[0];
  const float* A      = (const float*)d_in[1];
  const float* alpha  = (const float*)d_in[2];
  const float* beta   = (const float*)d_in[3];
  const float* W_pre  = (const float*)d_in[4];
  const float* b_pre  = (const float*)d_in[5];
  const float* bn_pre = (const float*)d_in[6];
  const float* W1     = (const float*)d_in[7];
  const float* b1     = (const float*)d_in[8];
  const float* W2     = (const float*)d_in[9];
  const float* b2     = (const float*)d_in[10];
  const float* W_post = (const float*)d_in[11];
  const float* b_post = (const float*)d_in[12];
  const float* bn_post= (const float*)d_in[13];
  const float* W_down = (const float*)d_in[14];
  const float* b_down = (const float*)d_in[15];
  const float* bn_down= (const float*)d_in[16];
  float* out = (float*)d_out;

  gm_tmp  <<<cN * 16,  256, 0, stream>>>(x, W_pre, b_pre, bn_pre,
                                         W_post, b_post, bn_post,
                                         W_down, b_down, bn_down);
  gm_prep <<<cN * 3,   512, 0, stream>>>(W1, b1, W2, b2, A, alpha, beta);
  gm_fused<<<cN * 16,  512, 0, stream>>>(x, out);
}

// Round 15
// 161.090 us; speedup vs baseline: 5.5860x; 1.0174x over previous
//
#include <hip/hip_runtime.h>
#include <hip/hip_bf16.h>

typedef __hip_bfloat16 bf16;
typedef __attribute__((ext_vector_type(8))) short s16x8;
typedef __attribute__((ext_vector_type(4))) float f32x4;

constexpr int cN = 128, cC = 64, cT = 64, cV = 25, cK = 3, cMID = 64, cKM = 192, cTV = 1600;
constexpr float cEPS = 1e-5f;

// BSS intermediates (no d_ws use). All rewritten before read each call.
__device__ float g_tmp[cN * cC * cV];
// Per-channel Adyn in B-fragment order: [n][r][nf(2)][lane(64)][j(8)] bf16
__device__ ushort g_adF[(size_t)cN * cKM * 1024];          // 50.3 MB
// Folded weights in A-fragment order: [k-step][m-frag(12)][lane(64)][8]
__device__ ushort g_WpreF[2 * 12 * 512];
__device__ ushort g_WcatF[8 * 12 * 512];
__device__ float g_bpre [cKM];
__device__ float g_cterm[cKM];

__device__ __forceinline__ ushort f2bu(float v){ return __builtin_bit_cast(ushort, __float2bfloat16(v)); }

// Zl fragment index with bank swizzle: 4 g-groups read same cols at oct
// stride 128*16B (bank-invariant) -> XOR oct's low 2 bits into col bits 1..2
// spreads them over disjoint 4-dword windows.  Returns ushort offset.
__device__ __forceinline__ int zidx(int oct, int col){
  return (oct*128 + (col ^ ((oct & 3) << 1))) * 8;
}

// ---------------------------------------------------------------------------
// 1) g_tmp[n,c,v] = mean_t x[n,c,t,v]  (grid = N*16) + blocks 0..7 also fold
//    bn into weights/biases (A-frag order) as a side job.
// ---------------------------------------------------------------------------
__global__ __launch_bounds__(256) void gm_tmp(const float* __restrict__ x,
    const float* __restrict__ Wpre, const float* __restrict__ bpre,
    const float* __restrict__ bnpre,
    const float* __restrict__ Wpost, const float* __restrict__ bpost,
    const float* __restrict__ bnpost,
    const float* __restrict__ Wdown, const float* __restrict__ bdown,
    const float* __restrict__ bndown){
  __shared__ float xs[4 * cTV];
  int n = blockIdx.x >> 4, cg = blockIdx.x & 15;
  int tid = threadIdx.x;
  const float* xp = x + ((size_t)n*cC + cg*4)*cTV;
  for (int i = tid; i < 4*cTV; i += 256) xs[i] = xp[i];
  __syncthreads();
  if (tid < 100){
    int c = tid / 25, v = tid - c*25;
    float s = 0.f;
    #pragma unroll
    for (int t = 0; t < cT; ++t) s += xs[c*cTV + t*cV + v];
    g_tmp[(n*cC + cg*4 + c)*cV + v] = s * (1.f/cT);
  }
  // ---- fold side-job on blocks 0..7 (24 o's each) ----
  if (blockIdx.x >= 8) return;
  __syncthreads();                    // xs reuse
  float* sPre  = xs;
  float* sPost = xs + 32;
  float* sDown = xs + 64;
  int ob = blockIdx.x * 24;
  if (tid < 24){
    int o = ob + tid;
    float sp = bnpre[o] * rsqrtf(bnpre[3*cKM+o] + cEPS);
    sPre[tid] = sp;
    g_bpre[o] = bpre[o]*sp + bnpre[cKM+o] - bnpre[2*cKM+o]*sp;
    float sP = bnpost[o] * rsqrtf(bnpost[3*cKM+o] + cEPS);
    float sD = bndown[o] * rsqrtf(bndown[3*cKM+o] + cEPS);
    sPost[tid] = sP; sDown[tid] = sD;
    g_cterm[o] = bpost[o]*sP + bnpost[cKM+o] - bnpost[2*cKM+o]*sP
               + bdown[o]*sD + bndown[cKM+o] - bndown[2*cKM+o]*sD;
  }
  __syncthreads();
  for (int i = tid; i < 24*cC; i += 256){
    int ol = i >> 6, k = i & 63;
    int o = ob + ol;
    int step = k >> 5, g = (k >> 3) & 3, j = k & 7;
    int dst = ((step*12 + (o>>4)) << 9) + (((g<<4) | (o&15)) << 3) + j;
    g_WpreF[dst] = f2bu(Wpre[o*cC + k] * sPre[ol]);
  }
  for (int i = tid; i < 24*256; i += 256){
    int ol = i >> 8, k = i & 255;
    int o = ob + ol;
    float w = (k < cKM) ? Wpost[o*cKM + k] * sPost[ol]
                        : Wdown[o*cC + (k - cKM)] * sDown[ol];
    int step = k >> 5, g = (k >> 3) & 3, j = k & 7;
    int dst = ((step*12 + (o>>4)) << 9) + (((g<<4) | (o&15)) << 3) + j;
    g_WcatF[dst] = f2bu(w);
  }
}

// ---------------------------------------------------------------------------
// 2) PREP: x1x2 -> gram -> softmax -> adF assembly.  grid = N*3, 512 thr.
//    (unchanged from r14)
// ---------------------------------------------------------------------------
__global__ __launch_bounds__(512) void gm_prep(
    const float* __restrict__ W1, const float* __restrict__ b1,
    const float* __restrict__ W2, const float* __restrict__ b2,
    const float* __restrict__ A,  const float* __restrict__ alpha,
    const float* __restrict__ beta){
  __shared__ float tl [cC*cV + 32];   // tmp slice (+pad: reads up to v=31)
  __shared__ float w1l[cMID*65];      // 16.6 KB, row-padded -> conflict-free
  __shared__ float w2l[cMID*65];
  __shared__ float x1l[cMID*cV];
  __shared__ float x2l[cMID*cV];
  __shared__ float Al [cV*cV];        // A, later A + ada
  __shared__ float adal[cV*cV];
  int bid = blockIdx.x; int n = bid / 3, kg = bid % 3;
  int tid = threadIdx.x;
  for (int i = tid; i < cC*cV; i += 512) tl[i] = g_tmp[n*cC*cV + i];
  if (tid < 32) tl[cC*cV + tid] = 0.f;
  for (int i = tid; i < cV*cV; i += 512) Al[i] = A[kg*625 + i];
  for (int i = tid; i < cMID*cC; i += 512){
    int ch = i >> 6, c = i & 63;
    w1l[ch*65 + c] = W1[(kg*cMID + ch)*cC + c];
    w2l[ch*65 + c] = W2[(kg*cMID + ch)*cC + c];
  }
  __syncthreads();
  {
    int ch = tid >> 3, iv = tid & 7;
    int o = kg*cMID + ch;
    float bb1 = b1[o], bb2 = b2[o];
    float s1[4] = {bb1, bb1, bb1, bb1};
    float s2[4] = {bb2, bb2, bb2, bb2};
    #pragma unroll 8
    for (int c = 0; c < cC; ++c){
      float w1c = w1l[ch*65 + c], w2c = w2l[ch*65 + c];
      #pragma unroll
      for (int k = 0; k < 4; ++k){
        float t = tl[c*cV + iv + 8*k];
        s1[k] += w1c * t;
        s2[k] += w2c * t;
      }
    }
    #pragma unroll
    for (int k = 0; k < 4; ++k){
      int v = iv + 8*k;
      if (v < cV){ x1l[ch*cV + v] = s1[k]; x2l[ch*cV + v] = s2[k]; }
    }
  }
  __syncthreads();
  for (int idx = tid; idx < cV*cV; idx += 512){
    int v = idx / cV, w = idx % cV;
    float s = 0.f;
    #pragma unroll 8
    for (int c = 0; c < cMID; ++c) s += x1l[c*cV + v] * x2l[c*cV + w];
    adal[idx] = s;
  }
  __syncthreads();
  float b0 = beta[0];
  if (tid < cV){
    int w = tid;
    float m = -1e30f;
    for (int v = 0; v < cV; ++v) m = fmaxf(m, adal[v*cV + w]);
    float s = 0.f;
    for (int v = 0; v < cV; ++v) s += __expf(adal[v*cV + w] - m);
    float inv = b0 / s;
    for (int v = 0; v < cV; ++v) adal[v*cV + w] = __expf(adal[v*cV + w] - m) * inv;
  }
  __syncthreads();
  for (int i = tid; i < cV*cV; i += 512) Al[i] += adal[i];
  __syncthreads();
  float a0 = alpha[0];
  int rem = tid * 2;
  int nf = rem >> 9, r2 = rem & 511;
  int li = r2 >> 3, j0 = r2 & 7;
  int v0 = 8*(li >> 4) + j0, w = 16*nf + (li & 15);
  bool wok = (w < cV);
  bool v0ok = wok && (v0 < cV), v1ok = wok && (v0 + 1 < cV);
  float AW0 = v0ok ? Al[v0*cV + w] : 0.f;
  float AW1 = v1ok ? Al[(v0+1)*cV + w] : 0.f;
  uint* dst = (uint*)(g_adF + ((size_t)n*cKM + kg*cMID)*1024 + rem);
  #pragma unroll 4
  for (int ch = 0; ch < cMID; ++ch){
    float f0 = 0.f, f1 = 0.f;
    if (wok){
      float xw = x2l[ch*cV + w];
      if (v0ok){
        float e2 = __expf(2.f*(x1l[ch*cV + v0] - xw));
        f0 = __fdividef(e2 - 1.f, e2 + 1.f)*a0 + AW0;
      }
      if (v1ok){
        float e2 = __expf(2.f*(x1l[ch*cV + v0 + 1] - xw));
        f1 = __fdividef(e2 - 1.f, e2 + 1.f)*a0 + AW1;
      }
    }
    dst[(size_t)ch * 512] = (uint)f2bu(f0) | ((uint)f2bu(f1) << 16);
  }
}

// ---------------------------------------------------------------------------
// 3) FUSED pre -> per-channel map -> out.  One block per (n, 4-t tile).
//    512 thr = 8 waves.  LDS 80 KB -> 2 blocks/CU.
//    r15: (a) Zl column XOR-swizzle -> GEMM1/3 b128 reads <=2-way;
//         (b) n-contiguous XCD swizzle -> adF L2-resident;
//         (c) GEMM2 channel-pair u32-packed LDS stores.
// ---------------------------------------------------------------------------
__global__ __launch_bounds__(512, 4) void gm_fused(const float* __restrict__ x,
                                                   float* __restrict__ outf){
  __shared__ ushort Zl[32 * 128 * 8];      // 64 KB [oct][col^swz][j]
  __shared__ ushort Pt[64 * 128];          // 16 KB [chl][slot][t][8]
  // n-contiguous XCD swizzle: an n's 16 blocks land consecutively on ONE XCD
  int c8 = (int)blockIdx.x & 7, i8 = (int)blockIdx.x >> 3;
  int n = c8 + 8*(i8 >> 4), ttile = i8 & 15;
  int t0 = ttile * 4;
  int tid = threadIdx.x;
  int wv = tid >> 6, lane = tid & 63, g = lane >> 4, l15 = lane & 15;
  int mfh = wv >> 1;          // 0..3
  int nfh = wv & 1;           // 0..1

  // ---- stage x -> Z octets 24..31 (pads zero) ----
  #pragma unroll
  for (int s0 = 0; s0 < 1024; s0 += 512){
    int s = s0 + tid;
    int oct = 24 + (s >> 7), col = s & 127;
    int t = col >> 5, v = col & 31;
    ushort u[8];
    if (v < cV){
      const float* xp = x + ((size_t)n*cC + (oct-24)*8)*cTV + (t0 + t)*cV + v;
      #pragma unroll
      for (int j = 0; j < 8; ++j) u[j] = f2bu(xp[(size_t)j*cTV]);
    } else {
      #pragma unroll
      for (int j = 0; j < 8; ++j) u[j] = 0;
    }
    *(uint4*)&Zl[zidx(oct, col)] = *(const uint4*)u;
  }

  #pragma unroll 1
  for (int kg = 0; kg < 3; ++kg){
    __syncthreads();   // kg=0: x staged; kg>0: Pt safe to overwrite
    // ---- prefetch this kg's adF B-frags (hidden under GEMM1; L2-hot) ----
    s16x8 bva0[8], bva1[8];
    #pragma unroll
    for (int cc = 0; cc < 8; ++cc){
      const ushort* bp = g_adF + ((size_t)n*cKM + kg*64 + wv*8 + cc)*1024;
      bva0[cc] = *(const s16x8*)(bp + lane*8);
      bva1[cc] = *(const s16x8*)(bp + 512 + lane*8);
    }
    // ---- GEMM1: pre rows kg*64..kg*64+63, 128 cols ----
    f32x4 a1[4];
    #pragma unroll
    for (int nn = 0; nn < 4; ++nn) a1[nn] = (f32x4){0.f,0.f,0.f,0.f};
    #pragma unroll
    for (int ks = 0; ks < 2; ++ks){
      s16x8 av = *(const s16x8*)(g_WpreF + ((ks*12 + kg*4 + mfh) << 9) + lane*8);
      #pragma unroll
      for (int nn = 0; nn < 4; ++nn){
        int col = 16*(nfh*4 + nn) + l15;
        s16x8 bv = *(const s16x8*)&Zl[zidx(24 + ks*4 + g, col)];
        a1[nn] = __builtin_amdgcn_mfma_f32_16x16x32_bf16(av, bv, a1[nn], 0, 0, 0);
      }
    }
    // bias+relu -> Pt (zero pads), XOR-swizzled slot
    #pragma unroll
    for (int nn = 0; nn < 4; ++nn){
      int col = 16*(nfh*4 + nn) + l15;
      int t = col >> 5, v = col & 31;
      #pragma unroll
      for (int q = 0; q < 4; ++q){
        int o = 16*mfh + 4*g + q;
        float val = (v < cV) ? fmaxf(a1[nn][q] + g_bpre[kg*64 + o], 0.f) : 0.f;
        int slot = ((v>>3) ^ (o>>2)) & 3;
        Pt[o*128 + slot*32 + t*8 + (v & 7)] = f2bu(val);
      }
    }
    __syncthreads();
    // ---- GEMM2 per channel-pair: D[t(pad16), w] = pre[t,v] @ Adyn[v,w] ----
    int octY = kg*8 + wv;                  // this wave's y octet
    #pragma unroll
    for (int cc = 0; cc < 8; cc += 2){
      int chlE = wv*8 + cc, chlO = chlE + 1;
      s16x8 avE, avO;
      if (l15 < 4){
        int slotE = (g ^ (chlE>>2)) & 3;
        avE = *(const s16x8*)&Pt[chlE*128 + slotE*32 + l15*8];
        avO = *(const s16x8*)&Pt[chlO*128 + slotE*32 + l15*8];  // same slot (chl>>2 equal)
      } else { avE = (s16x8){0,0,0,0,0,0,0,0}; avO = avE; }
      f32x4 d0e = __builtin_amdgcn_mfma_f32_16x16x32_bf16(avE, bva0[cc],   (f32x4){0.f,0.f,0.f,0.f}, 0, 0, 0);
      f32x4 d1e = __builtin_amdgcn_mfma_f32_16x16x32_bf16(avE, bva1[cc],   (f32x4){0.f,0.f,0.f,0.f}, 0, 0, 0);
      f32x4 d0o = __builtin_amdgcn_mfma_f32_16x16x32_bf16(avO, bva0[cc+1], (f32x4){0.f,0.f,0.f,0.f}, 0, 0, 0);
      f32x4 d1o = __builtin_amdgcn_mfma_f32_16x16x32_bf16(avO, bva1[cc+1], (f32x4){0.f,0.f,0.f,0.f}, 0, 0, 0);
      if (g == 0){
        #pragma unroll
        for (int q = 0; q < 4; ++q){       // q = t
          uint p0 = (uint)f2bu(d0e[q]) | ((uint)f2bu(d0o[q]) << 16);
          uint p1 = (uint)f2bu(d1e[q]) | ((uint)f2bu(d1o[q]) << 16);
          *(uint*)&Zl[zidx(octY, q*32 + l15)      + cc] = p0;
          *(uint*)&Zl[zidx(octY, q*32 + 16 + l15) + cc] = p1;
        }
      }
    }
  }
  __syncthreads();
  // ---- GEMM3: out[192][128] = Wcat[192][256] @ Z, rotated av prefetch ----
  f32x4 a3[3][4];
  #pragma unroll
  for (int mm = 0; mm < 3; ++mm)
    #pragma unroll
    for (int nn = 0; nn < 4; ++nn) a3[mm][nn] = (f32x4){0.f,0.f,0.f,0.f};
  s16x8 avc[3], avn[3];
  #pragma unroll
  for (int mm = 0; mm < 3; ++mm)
    avc[mm] = *(const s16x8*)(g_WcatF + ((0*12 + mfh*3 + mm) << 9) + lane*8);
  #pragma unroll 1
  for (int ks = 0; ks < 8; ++ks){
    if (ks < 7){
      #pragma unroll
      for (int mm = 0; mm < 3; ++mm)
        avn[mm] = *(const s16x8*)(g_WcatF + (((ks+1)*12 + mfh*3 + mm) << 9) + lane*8);
    }
    s16x8 bv[4];
    #pragma unroll
    for (int nn = 0; nn < 4; ++nn){
      int col = 16*(nfh*4 + nn) + l15;
      bv[nn] = *(const s16x8*)&Zl[zidx(ks*4 + g, col)];
    }
    #pragma unroll
    for (int mm = 0; mm < 3; ++mm)
      #pragma unroll
      for (int nn = 0; nn < 4; ++nn)
        a3[mm][nn] = __builtin_amdgcn_mfma_f32_16x16x32_bf16(avc[mm], bv[nn], a3[mm][nn], 0, 0, 0);
    #pragma unroll
    for (int mm = 0; mm < 3; ++mm) avc[mm] = avn[mm];
  }
  // epilogue: bias + relu -> d_out (f32)
  #pragma unroll
  for (int mm = 0; mm < 3; ++mm){
    #pragma unroll
    for (int q = 0; q < 4; ++q){
      int o = 48*mfh + 16*mm + 4*g + q;
      float ct = g_cterm[o];
      #pragma unroll
      for (int nn = 0; nn < 4; ++nn){
        int col = 16*(nfh*4 + nn) + l15;
        int t = col >> 5, v = col & 31;
        if (v < cV)
          outf[((size_t)n*cKM + o)*cTV + (t0 + t)*cV + v] = fmaxf(a3[mm][nn][q] + ct, 0.f);
      }
    }
  }
}

// ---------------------------------------------------------------------------
extern "C" void kernel_launch(void* const* d_in, const int* in_sizes, int n_in,
                              void* d_out, int out_size, void* d_ws, size_t ws_size,
                              hipStream_t stream){
  (void)in_sizes; (void)n_in; (void)out_size; (void)d_ws; (void)ws_size;
  const float* x      = (const float*)d_in[0];
  const float* A      = (const float*)d_in[1];
  const float* alpha  = (const float*)d_in[2];
  const float* beta   = (const float*)d_in[3];
  const float* W_pre  = (const float*)d_in[4];
  const float* b_pre  = (const float*)d_in[5];
  const float* bn_pre = (const float*)d_in[6];
  const float* W1     = (const float*)d_in[7];
  const float* b1     = (const float*)d_in[8];
  const float* W2     = (const float*)d_in[9];
  const float* b2     = (const float*)d_in[10];
  const float* W_post = (const float*)d_in[11];
  const float* b_post = (const float*)d_in[12];
  const float* bn_post= (const float*)d_in[13];
  const float* W_down = (const float*)d_in[14];
  const float* b_down = (const float*)d_in[15];
  const float* bn_down= (const float*)d_in[16];
  float* out = (float*)d_out;

  gm_tmp  <<<cN * 16,  256, 0, stream>>>(x, W_pre, b_pre, bn_pre,
                                         W_post, b_post, bn_post,
                                         W_down, b_down, bn_down);
  gm_prep <<<cN * 3,   512, 0, stream>>>(W1, b1, W2, b2, A, alpha, beta);
  gm_fused<<<cN * 16,  512, 0, stream>>>(x, out);
}